// Round 5
// baseline (411.384 us; speedup 1.0000x reference)
//
#include <hip/hip_runtime.h>
#include <hip/hip_bf16.h>

typedef short bf16x8 __attribute__((ext_vector_type(8)));
typedef short bf16x4 __attribute__((ext_vector_type(4)));
typedef float f32x4 __attribute__((ext_vector_type(4)));
typedef unsigned int u32;
typedef unsigned long long u64;

#define GLD_LDS16(gp, lp) \
  __builtin_amdgcn_global_load_lds((const __attribute__((address_space(1))) u32*)(gp), \
                                   (__attribute__((address_space(3))) u32*)(lp), 16, 0, 0)

__device__ __forceinline__ short f2bf(float f) {
  u32 u = __builtin_bit_cast(u32, f);
  u = (u + 0x7fffu + ((u >> 16) & 1u)) >> 16;
  return (short)u;
}

// gfx950 hardware packed f32->bf16 (v_cvt_pk_bf16_f32); fallback to manual RNE.
__device__ __forceinline__ u32 pack2_bf16(float a, float b) {
#if __has_builtin(__builtin_amdgcn_cvt_pk_bf16_f32)
  typedef __bf16 bf16v2 __attribute__((ext_vector_type(2)));
  bf16v2 r = __builtin_amdgcn_cvt_pk_bf16_f32(a, b);
  return __builtin_bit_cast(u32, r);
#else
  return (u32)(unsigned short)f2bf(a) | ((u32)(unsigned short)f2bf(b) << 16);
#endif
}

__device__ __forceinline__ float exp2_fast(float x) {
#if __has_builtin(__builtin_amdgcn_exp2f)
  return __builtin_amdgcn_exp2f(x);
#else
  return exp2f(x);
#endif
}

// K=16 bf16 MFMA: A,B = 4 bf16 (2 VGPRs).
__device__ __forceinline__ f32x4 mfma_16x16x16_bf16(bf16x4 a, bf16x4 b, f32x4 c) {
#if __has_builtin(__builtin_amdgcn_mfma_f32_16x16x16_bf16)
  return __builtin_amdgcn_mfma_f32_16x16x16_bf16(a, b, c, 0, 0, 0);
#elif __has_builtin(__builtin_amdgcn_mfma_f32_16x16x16bf16_1k)
  return __builtin_amdgcn_mfma_f32_16x16x16bf16_1k(a, b, c, 0, 0, 0);
#else
  f32x4 d = c;
  __asm__ volatile("v_mfma_f32_16x16x16_bf16 %0, %1, %2, %0\n\ts_nop 7\n\ts_nop 7"
                   : "+v"(d) : "v"(a), "v"(b));
  return d;
#endif
}

// ---------------- small prep kernels ----------------

__global__ void cvt_f32_bf16(const float* __restrict__ in, short* __restrict__ out, int n4) {
  int i = (blockIdx.x * 256 + threadIdx.x) * 4;
  float4 v = *(const float4*)(in + i);
  short4 o;
  o.x = f2bf(v.x); o.y = f2bf(v.y); o.z = f2bf(v.z); o.w = f2bf(v.w);
  *(short4*)(out + i) = o;
}

__global__ void rope_tables(const float* __restrict__ rpe, float* __restrict__ cosT,
                            float* __restrict__ sinT) {
  int i = blockIdx.x * 256 + threadIdx.x;  // 32768 = 1024*32
  float v = rpe[i];
  cosT[i] = cosf(v);
  sinT[i] = sinf(v);
}

// u64 bitmask per (b, q-row, key-tile-of-64): 1 MB total, L3-resident.
__global__ void mask_pack(const int* __restrict__ m, u64* __restrict__ out) {
  int i = blockIdx.x * 256 + threadIdx.x;  // 8*1024*1024 threads
  u64 bm = __ballot(m[i] != 0);
  if ((threadIdx.x & 63) == 0) out[i >> 6] = bm;
}

// ---------------- GEMM 1: QKV projection + bias + RoPE + scatter ----------------
// X (8192,1024) bf16, W (3072,1024) bf16; C = X * W^T. Tile 128x128, BK=32.
// MFMA operands SWAPPED (mfma(b,a)) so D row=channel, col=token: each lane holds
// 4 consecutive channels of one token -> in-register RoPE pairs, 8 B stores.
// q pre-scaled by 0.125 * log2(e) so flash softmax runs in exp2 domain.
__global__ __launch_bounds__(256, 2) void gemm_qkv(
    const short* __restrict__ Xb, const short* __restrict__ Wb,
    const float* __restrict__ bqkv, const float* __restrict__ cosT,
    const float* __restrict__ sinT, short* __restrict__ qb,
    short* __restrict__ kbuf, short* __restrict__ vbuf) {
  __shared__ short Ash[128 * 32];
  __shared__ short Bsh[128 * 32];
  const int tid = threadIdx.x;
  const int wid = tid >> 6, lane = tid & 63;
  const int g = lane >> 4, c = lane & 15;
  const int wm = wid >> 1, wn = wid & 1;
  const int m0 = blockIdx.y * 128, n0 = blockIdx.x * 128;

  f32x4 acc[4][4];
  for (int i = 0; i < 4; i++)
    for (int j = 0; j < 4; j++) acc[i][j] = (f32x4){0.f, 0.f, 0.f, 0.f};

  const int srow = lane >> 2;
  const int scol = (lane & 3) * 8;
  const short* AgL = Xb + (long)(m0 + wid * 32 + srow) * 1024 + scol;
  const short* BgL = Wb + (long)(n0 + wid * 32 + srow) * 1024 + scol;
  short* As0 = &Ash[(wid * 32) * 32];
  short* As1 = &Ash[(wid * 32 + 16) * 32];
  short* Bs0 = &Bsh[(wid * 32) * 32];
  short* Bs1 = &Bsh[(wid * 32 + 16) * 32];

  for (int kt = 0; kt < 32; ++kt) {
    const int ko = kt * 32;
    GLD_LDS16(AgL + ko, As0);
    GLD_LDS16(AgL + ko + 16 * 1024, As1);
    GLD_LDS16(BgL + ko, Bs0);
    GLD_LDS16(BgL + ko + 16 * 1024, Bs1);
    __syncthreads();
    bf16x8 af[4], bfr[4];
    for (int i = 0; i < 4; i++)
      af[i] = *(const bf16x8*)&Ash[(wm * 64 + i * 16 + c) * 32 + g * 8];
    for (int j = 0; j < 4; j++)
      bfr[j] = *(const bf16x8*)&Bsh[(wn * 64 + j * 16 + c) * 32 + g * 8];
    for (int i = 0; i < 4; i++)
      for (int j = 0; j < 4; j++)
        acc[i][j] = __builtin_amdgcn_mfma_f32_16x16x32_bf16(bfr[j], af[i], acc[i][j], 0, 0, 0);
    __syncthreads();
  }

  // epilogue: lane owns token r (col=c), 4 consecutive channels (rows=quad*4+reg)
  for (int jt = 0; jt < 4; jt++) {
    const int chan = n0 + wn * 64 + jt * 16 + g * 4;  // %4 == 0
    const int three = chan >> 10;
    const int hh = (chan >> 6) & 15;
    const int d = chan & 63;
    const float4 bq = *(const float4*)&bqkv[chan];
    for (int i = 0; i < 4; i++) {
      const int r = m0 + wm * 64 + i * 16 + c;
      const int l = r >> 3, b = r & 7;
      float v0 = acc[i][jt][0] + bq.x;
      float v1 = acc[i][jt][1] + bq.y;
      float v2 = acc[i][jt][2] + bq.z;
      float v3 = acc[i][jt][3] + bq.w;
      const long doff = ((long)(b * 16 + hh) * 1024 + l) * 64 + d;
      if (three == 2) {
        uint2 o = {pack2_bf16(v0, v1), pack2_bf16(v2, v3)};
        *(uint2*)&vbuf[doff] = o;
      } else {
        const float4 cs = *(const float4*)&cosT[l * 32 + (d & 31)];
        const float4 sn = *(const float4*)&sinT[l * 32 + (d & 31)];
        float e0 = v0 * cs.x - v1 * sn.x;
        float o0 = v1 * cs.y + v0 * sn.y;
        float e1 = v2 * cs.z - v3 * sn.z;
        float o1 = v3 * cs.w + v2 * sn.w;
        short* dst;
        if (three == 0) {
          const float S = 0.18033688011f;  // 1/sqrt(D) * log2(e)
          e0 *= S; o0 *= S; e1 *= S; o1 *= S;
          dst = qb;
        } else {
          dst = kbuf;
        }
        uint2 o = {pack2_bf16(e0, o0), pack2_bf16(e1, o1)};
        *(uint2*)&dst[doff] = o;
      }
    }
  }
}

// ---------------- V transpose: (B,H,L,D) -> (B,H,D,L) ----------------
__global__ __launch_bounds__(256) void transpose_v(const short* __restrict__ vbuf,
                                                   short* __restrict__ vTb) {
  __shared__ short T[64 * 72];
  const int bh = blockIdx.y;
  const int l0 = blockIdx.x * 64;
  const int t = threadIdx.x;
  const int row = t >> 3;
  const int cc = (t & 7) * 8;
  const short* src = vbuf + ((long)bh * 1024 + l0) * 64;
  for (int p = 0; p < 2; p++) {
    int lr = row + p * 32;
    *(bf16x8*)&T[lr * 72 + cc] = *(const bf16x8*)&src[(long)lr * 64 + cc];
  }
  __syncthreads();
  short* dst = vTb + (long)bh * 64 * 1024 + l0;
  for (int p = 0; p < 2; p++) {
    int d = row + p * 32;
    bf16x8 v;
    for (int j = 0; j < 8; j++) v[j] = T[(cc + j) * 72 + d];
    *(bf16x8*)&dst[(long)d * 1024 + cc] = v;
  }
}

// ---------------- flash attention v5 ----------------
// S^T formulation, register P, async double-buffered global_load_lds staging.
// 512-thread blocks: 8 waves x 16 q-rows = 128 q-rows share one K/V staging ->
// 2x compute per barrier (latency hiding), half the K/V L2 traffic per q-row.
// u64 bitmask (L3-resident), expanded in-register to bf16 AND-masks.
__global__ __launch_bounds__(512, 8) void flash_attn(
    const short* __restrict__ qb, const short* __restrict__ kbuf,
    const short* __restrict__ vTb, const u64* __restrict__ maskb,
    short* __restrict__ attno) {
  __shared__ short K0[64 * 64], K1[64 * 64];
  __shared__ short V0[64 * 64], V1[64 * 64];
  const int t = threadIdx.x;
  const int wid = t >> 6, lane = t & 63;
  const int g = lane >> 4, c = lane & 15;
  const int q0 = blockIdx.x * 128;
  const int bh = blockIdx.y;
  const int b = bh >> 4;
  const int h = bh & 15;
  const long qoff = (long)bh * 1024 * 64;
  const int qrow = q0 + wid * 16 + c;  // this lane's q column

  // Q fragment (B-operand of S^T mfma)
  bf16x8 aq0, aq1;
  {
    const short* qp = qb + qoff + (long)qrow * 64;
    aq0 = *(const bf16x8*)(qp + g * 8);
    aq1 = *(const bf16x8*)(qp + 32 + g * 8);
  }

  f32x4 Od[4];
  for (int i = 0; i < 4; i++) Od[i] = (f32x4){0.f, 0.f, 0.f, 0.f};
  f32x4 Ld = (f32x4){0.f, 0.f, 0.f, 0.f};  // row-sum acc: D[0][q] = sum_k P[k][q]
  float m_run = -1e30f;

  // ones-row A-operand: lanes with m-index 0 hold bf16 1.0 across k
  bf16x4 avOnes;
  {
    union { bf16x4 v; u32 u[2]; } av;
    av.u[0] = av.u[1] = (c == 0) ? 0x3F803F80u : 0u;
    avOnes = av.v;
  }

  const u64* mrow = maskb + ((long)b * 1024 + qrow) * 16;
  const short* Kg = kbuf + qoff;
  const short* Vg = vTb + qoff;

  // staging: 8 waves x 8 rows each; lane l fetches global chunk (l&7)^(l>>3) of
  // row wid*8+(l>>3) -> lands at LDS chunk pos l&7 (net: chunk cg at pos cg^(row&7)).
  const int l8 = lane >> 3, l7 = lane & 7;
  const int sr = wid * 8 + l8;
  const int sch = ((l7 ^ l8) & 7) * 8;

  // fragment read offsets (shorts, within a 64x64 tile buffer)
  const int ck0 = g ^ (c & 7);
  const int kOff0 = c * 64 + ck0 * 8;
  const int kOff1 = c * 64 + (ck0 ^ 4) * 8;
  int vOff[4];
  for (int nt = 0; nt < 4; nt++)
    vOff[nt] = c * 64 + (((2 * nt + (g >> 1)) ^ (c & 7)) * 8) + (g & 1) * 4;

#define STAGE(KD, VD, ktn) do { \
    GLD_LDS16(Kg + (long)((ktn) + sr) * 64 + sch, &KD[(wid * 8) * 64]); \
    GLD_LDS16(Vg + (long)sr * 1024 + (ktn) + sch, &VD[(wid * 8) * 64]); \
  } while (0)

#define TILE(KB, VB, KP, VP, ki) do { \
    u64 mw = mrow[ki]; \
    __syncthreads(); /* drains prefetch issued a full tile of compute ago */ \
    STAGE(KP, VP, (((ki) + 1) & 15) * 64); \
    f32x4 z[4]; \
    for (int nt = 0; nt < 4; nt++) { \
      bf16x8 bk0 = *(const bf16x8*)&KB[kOff0 + nt * 1024]; \
      bf16x8 bk1 = *(const bf16x8*)&KB[kOff1 + nt * 1024]; \
      f32x4 zz = (f32x4){0.f, 0.f, 0.f, 0.f}; \
      zz = __builtin_amdgcn_mfma_f32_16x16x32_bf16(bk0, aq0, zz, 0, 0, 0); \
      zz = __builtin_amdgcn_mfma_f32_16x16x32_bf16(bk1, aq1, zz, 0, 0, 0); \
      z[nt] = zz; \
    } \
    float mx = fmaxf(fmaxf(z[0][0], z[0][1]), fmaxf(z[0][2], z[0][3])); \
    for (int nt = 1; nt < 4; nt++) \
      mx = fmaxf(mx, fmaxf(fmaxf(z[nt][0], z[nt][1]), fmaxf(z[nt][2], z[nt][3]))); \
    mx = fmaxf(mx, __shfl_xor(mx, 16, 64)); \
    mx = fmaxf(mx, __shfl_xor(mx, 32, 64)); \
    float mnew = fmaxf(m_run, mx); \
    if (__ballot(mnew > m_run)) { \
      float al = exp2_fast(m_run - mnew); \
      for (int dt = 0; dt < 4; dt++) { \
        Od[dt][0] *= al; Od[dt][1] *= al; Od[dt][2] *= al; Od[dt][3] *= al; \
      } \
      Ld[0] *= al; \
      m_run = mnew; \
    } \
    bf16x4 pb[4]; \
    for (int nt = 0; nt < 4; nt++) { \
      u32 m4 = (u32)(mw >> (nt * 16 + g * 4)) & 0xFu; \
      u32 mlo = ((m4 & 1u) ? 0xFFFFu : 0u) | ((m4 & 2u) ? 0xFFFF0000u : 0u); \
      u32 mhi = ((m4 & 4u) ? 0xFFFFu : 0u) | ((m4 & 8u) ? 0xFFFF0000u : 0u); \
      float p0 = exp2_fast(z[nt][0] - mnew); \
      float p1 = exp2_fast(z[nt][1] - mnew); \
      float p2 = exp2_fast(z[nt][2] - mnew); \
      float p3 = exp2_fast(z[nt][3] - mnew); \
      union { bf16x4 v; u32 u[2]; } pu; \
      pu.u[0] = pack2_bf16(p0, p1) & mlo; \
      pu.u[1] = pack2_bf16(p2, p3) & mhi; \
      pb[nt] = pu.v; \
    } \
    for (int nt = 0; nt < 4; nt++) { \
      Ld = mfma_16x16x16_bf16(avOnes, pb[nt], Ld); \
      for (int dt = 0; dt < 4; dt++) { \
        bf16x4 av = *(const bf16x4*)&VB[vOff[nt] + dt * 1024]; \
        Od[dt] = mfma_16x16x16_bf16(av, pb[nt], Od[dt]); \
      } \
    } \
  } while (0)

  STAGE(K0, V0, 0);
  for (int ki = 0; ki < 16; ki += 2) {
    TILE(K0, V0, K1, V1, ki);
    TILE(K1, V1, K0, V0, ki + 1);
  }
#undef TILE
#undef STAGE

  // l for q=c lives in lane c (reg 0 of quad 0); broadcast then normalize+store
  float lsum = __shfl(Ld[0], c, 64);
  float inv = 1.f / lsum;
  long rbase = ((long)qrow * 8 + b) * 1024 + h * 64 + g * 4;
  for (int dt = 0; dt < 4; dt++) {
    union { bf16x4 v; u32 u[2]; } o;
    o.u[0] = pack2_bf16(Od[dt][0] * inv, Od[dt][1] * inv);
    o.u[1] = pack2_bf16(Od[dt][2] * inv, Od[dt][3] * inv);
    *(bf16x4*)&attno[rbase + dt * 16] = o.v;
  }
}

// ---------------- GEMM 2: out = attno * Wo^T + bo (f32 out) ----------------
__global__ __launch_bounds__(256, 2) void gemm_out(
    const short* __restrict__ Ab, const short* __restrict__ Wob,
    const float* __restrict__ bo, float* __restrict__ out) {
  __shared__ short Ash[128 * 32];
  __shared__ short Bsh[128 * 32];
  const int tid = threadIdx.x;
  const int wid = tid >> 6, lane = tid & 63;
  const int g = lane >> 4, c = lane & 15;
  const int wm = wid >> 1, wn = wid & 1;
  const int m0 = blockIdx.y * 128, n0 = blockIdx.x * 128;

  f32x4 acc[4][4];
  for (int i = 0; i < 4; i++)
    for (int j = 0; j < 4; j++) acc[i][j] = (f32x4){0.f, 0.f, 0.f, 0.f};

  const int srow = lane >> 2;
  const int scol = (lane & 3) * 8;
  const short* AgL = Ab + (long)(m0 + wid * 32 + srow) * 1024 + scol;
  const short* BgL = Wob + (long)(n0 + wid * 32 + srow) * 1024 + scol;
  short* As0 = &Ash[(wid * 32) * 32];
  short* As1 = &Ash[(wid * 32 + 16) * 32];
  short* Bs0 = &Bsh[(wid * 32) * 32];
  short* Bs1 = &Bsh[(wid * 32 + 16) * 32];

  for (int kt = 0; kt < 32; ++kt) {
    const int ko = kt * 32;
    GLD_LDS16(AgL + ko, As0);
    GLD_LDS16(AgL + ko + 16 * 1024, As1);
    GLD_LDS16(BgL + ko, Bs0);
    GLD_LDS16(BgL + ko + 16 * 1024, Bs1);
    __syncthreads();
    bf16x8 af[4], bfr[4];
    for (int i = 0; i < 4; i++)
      af[i] = *(const bf16x8*)&Ash[(wm * 64 + i * 16 + c) * 32 + g * 8];
    for (int j = 0; j < 4; j++)
      bfr[j] = *(const bf16x8*)&Bsh[(wn * 64 + j * 16 + c) * 32 + g * 8];
    for (int i = 0; i < 4; i++)
      for (int j = 0; j < 4; j++)
        acc[i][j] = __builtin_amdgcn_mfma_f32_16x16x32_bf16(af[i], bfr[j], acc[i][j], 0, 0, 0);
    __syncthreads();
  }

  for (int jt = 0; jt < 4; jt++) {
    const int j = n0 + wn * 64 + jt * 16 + c;
    const float bias = bo[j];
    for (int i = 0; i < 4; i++) {
      const int rbase = m0 + wm * 64 + i * 16 + g * 4;
      for (int reg = 0; reg < 4; reg++)
        out[(long)(rbase + reg) * 1024 + j] = acc[i][jt][reg] + bias;
    }
  }
}

// ---------------- launcher ----------------
extern "C" void kernel_launch(void* const* d_in, const int* in_sizes, int n_in,
                              void* d_out, int out_size, void* d_ws, size_t ws_size,
                              hipStream_t stream) {
  const float* hs = (const float*)d_in[0];
  const float* rpe = (const float*)d_in[1];
  const int* amask = (const int*)d_in[2];
  const float* Wqkv = (const float*)d_in[3];
  const float* bqkv = (const float*)d_in[4];
  const float* Wo = (const float*)d_in[5];
  const float* bo = (const float*)d_in[6];
  float* out = (float*)d_out;

  char* ws = (char*)d_ws;
  auto alloc = [&](size_t bytes) {
    char* p = ws;
    ws += (bytes + 255) & ~(size_t)255;
    return p;
  };
  short* Xb = (short*)alloc(8192LL * 1024 * 2);
  short* Wqkvb = (short*)alloc(3072LL * 1024 * 2);
  short* Wob = (short*)alloc(1024LL * 1024 * 2);
  float* cosT = (float*)alloc(1024 * 32 * 4);
  float* sinT = (float*)alloc(1024 * 32 * 4);
  u64* maskb = (u64*)alloc(8LL * 1024 * 16 * 8);
  short* qb = (short*)alloc(128LL * 1024 * 64 * 2);
  short* kbuf = (short*)alloc(128LL * 1024 * 64 * 2);
  short* vbuf = (short*)alloc(128LL * 1024 * 64 * 2);
  short* vTb = (short*)alloc(128LL * 1024 * 64 * 2);
  short* attno = (short*)alloc(8192LL * 1024 * 2);

  cvt_f32_bf16<<<8192 * 1024 / 4 / 256, 256, 0, stream>>>(hs, Xb, 8192 * 1024);
  cvt_f32_bf16<<<3072 * 1024 / 4 / 256, 256, 0, stream>>>(Wqkv, Wqkvb, 3072 * 1024);
  cvt_f32_bf16<<<1024 * 1024 / 4 / 256, 256, 0, stream>>>(Wo, Wob, 1024 * 1024);
  rope_tables<<<128, 256, 0, stream>>>(rpe, cosT, sinT);
  mask_pack<<<32768, 256, 0, stream>>>(amask, maskb);
  gemm_qkv<<<dim3(24, 64), 256, 0, stream>>>(Xb, Wqkvb, bqkv, cosT, sinT, qb, kbuf, vbuf);
  transpose_v<<<dim3(16, 128), 256, 0, stream>>>(vbuf, vTb);
  flash_attn<<<dim3(8, 128), 512, 0, stream>>>(qb, kbuf, vTb, maskb, attno);
  gemm_out<<<dim3(8, 64), 256, 0, stream>>>(attno, Wob, bo, out);
}

// Round 6
// 345.058 us; speedup vs baseline: 1.1922x; 1.1922x over previous
//
#include <hip/hip_runtime.h>
#include <hip/hip_bf16.h>

typedef short bf16x8 __attribute__((ext_vector_type(8)));
typedef short bf16x4 __attribute__((ext_vector_type(4)));
typedef float f32x4 __attribute__((ext_vector_type(4)));
typedef unsigned int u32;
typedef unsigned long long u64;

#define GLD_LDS16(gp, lp) \
  __builtin_amdgcn_global_load_lds((const __attribute__((address_space(1))) u32*)(gp), \
                                   (__attribute__((address_space(3))) u32*)(lp), 16, 0, 0)

__device__ __forceinline__ short f2bf(float f) {
  u32 u = __builtin_bit_cast(u32, f);
  u = (u + 0x7fffu + ((u >> 16) & 1u)) >> 16;
  return (short)u;
}

// gfx950 hardware packed f32->bf16 (v_cvt_pk_bf16_f32); fallback to manual RNE.
__device__ __forceinline__ u32 pack2_bf16(float a, float b) {
#if __has_builtin(__builtin_amdgcn_cvt_pk_bf16_f32)
  typedef __bf16 bf16v2 __attribute__((ext_vector_type(2)));
  bf16v2 r = __builtin_amdgcn_cvt_pk_bf16_f32(a, b);
  return __builtin_bit_cast(u32, r);
#else
  return (u32)(unsigned short)f2bf(a) | ((u32)(unsigned short)f2bf(b) << 16);
#endif
}

__device__ __forceinline__ float exp2_fast(float x) {
#if __has_builtin(__builtin_amdgcn_exp2f)
  return __builtin_amdgcn_exp2f(x);
#else
  return exp2f(x);
#endif
}

// K=16 bf16 MFMA: A,B = 4 bf16 (2 VGPRs).
__device__ __forceinline__ f32x4 mfma_16x16x16_bf16(bf16x4 a, bf16x4 b, f32x4 c) {
#if __has_builtin(__builtin_amdgcn_mfma_f32_16x16x16_bf16)
  return __builtin_amdgcn_mfma_f32_16x16x16_bf16(a, b, c, 0, 0, 0);
#elif __has_builtin(__builtin_amdgcn_mfma_f32_16x16x16bf16_1k)
  return __builtin_amdgcn_mfma_f32_16x16x16bf16_1k(a, b, c, 0, 0, 0);
#else
  f32x4 d = c;
  __asm__ volatile("v_mfma_f32_16x16x16_bf16 %0, %1, %2, %0\n\ts_nop 7\n\ts_nop 7"
                   : "+v"(d) : "v"(a), "v"(b));
  return d;
#endif
}

// ---------------- small prep kernels ----------------

__global__ void cvt_f32_bf16(const float* __restrict__ in, short* __restrict__ out, int n4) {
  int i = (blockIdx.x * 256 + threadIdx.x) * 4;
  float4 v = *(const float4*)(in + i);
  short4 o;
  o.x = f2bf(v.x); o.y = f2bf(v.y); o.z = f2bf(v.z); o.w = f2bf(v.w);
  *(short4*)(out + i) = o;
}

__global__ void rope_tables(const float* __restrict__ rpe, float* __restrict__ cosT,
                            float* __restrict__ sinT) {
  int i = blockIdx.x * 256 + threadIdx.x;  // 32768 = 1024*32
  float v = rpe[i];
  cosT[i] = cosf(v);
  sinT[i] = sinf(v);
}

// u64 bitmask per (b, q-row, key-tile-of-64): 1 MB total, L3-resident.
__global__ void mask_pack(const int* __restrict__ m, u64* __restrict__ out) {
  int i = blockIdx.x * 256 + threadIdx.x;  // 8*1024*1024 threads
  u64 bm = __ballot(m[i] != 0);
  if ((threadIdx.x & 63) == 0) out[i >> 6] = bm;
}

// ---------------- GEMM 1: QKV projection + bias + RoPE + scatter ----------------
// X (8192,1024) bf16, W (3072,1024) bf16; C = X * W^T. Tile 128x128, BK=32.
// MFMA operands SWAPPED (mfma(b,a)) so D row=channel, col=token: each lane holds
// 4 consecutive channels of one token -> in-register RoPE pairs, 8 B stores.
// q pre-scaled by 0.125 * log2(e) so flash softmax runs in exp2 domain.
__global__ __launch_bounds__(256, 2) void gemm_qkv(
    const short* __restrict__ Xb, const short* __restrict__ Wb,
    const float* __restrict__ bqkv, const float* __restrict__ cosT,
    const float* __restrict__ sinT, short* __restrict__ qb,
    short* __restrict__ kbuf, short* __restrict__ vbuf) {
  __shared__ short Ash[128 * 32];
  __shared__ short Bsh[128 * 32];
  const int tid = threadIdx.x;
  const int wid = tid >> 6, lane = tid & 63;
  const int g = lane >> 4, c = lane & 15;
  const int wm = wid >> 1, wn = wid & 1;
  const int m0 = blockIdx.y * 128, n0 = blockIdx.x * 128;

  f32x4 acc[4][4];
  for (int i = 0; i < 4; i++)
    for (int j = 0; j < 4; j++) acc[i][j] = (f32x4){0.f, 0.f, 0.f, 0.f};

  const int srow = lane >> 2;
  const int scol = (lane & 3) * 8;
  const short* AgL = Xb + (long)(m0 + wid * 32 + srow) * 1024 + scol;
  const short* BgL = Wb + (long)(n0 + wid * 32 + srow) * 1024 + scol;
  short* As0 = &Ash[(wid * 32) * 32];
  short* As1 = &Ash[(wid * 32 + 16) * 32];
  short* Bs0 = &Bsh[(wid * 32) * 32];
  short* Bs1 = &Bsh[(wid * 32 + 16) * 32];

  for (int kt = 0; kt < 32; ++kt) {
    const int ko = kt * 32;
    GLD_LDS16(AgL + ko, As0);
    GLD_LDS16(AgL + ko + 16 * 1024, As1);
    GLD_LDS16(BgL + ko, Bs0);
    GLD_LDS16(BgL + ko + 16 * 1024, Bs1);
    __syncthreads();
    bf16x8 af[4], bfr[4];
    for (int i = 0; i < 4; i++)
      af[i] = *(const bf16x8*)&Ash[(wm * 64 + i * 16 + c) * 32 + g * 8];
    for (int j = 0; j < 4; j++)
      bfr[j] = *(const bf16x8*)&Bsh[(wn * 64 + j * 16 + c) * 32 + g * 8];
    for (int i = 0; i < 4; i++)
      for (int j = 0; j < 4; j++)
        acc[i][j] = __builtin_amdgcn_mfma_f32_16x16x32_bf16(bfr[j], af[i], acc[i][j], 0, 0, 0);
    __syncthreads();
  }

  // epilogue: lane owns token r (col=c), 4 consecutive channels (rows=quad*4+reg)
  for (int jt = 0; jt < 4; jt++) {
    const int chan = n0 + wn * 64 + jt * 16 + g * 4;  // %4 == 0
    const int three = chan >> 10;
    const int hh = (chan >> 6) & 15;
    const int d = chan & 63;
    const float4 bq = *(const float4*)&bqkv[chan];
    for (int i = 0; i < 4; i++) {
      const int r = m0 + wm * 64 + i * 16 + c;
      const int l = r >> 3, b = r & 7;
      float v0 = acc[i][jt][0] + bq.x;
      float v1 = acc[i][jt][1] + bq.y;
      float v2 = acc[i][jt][2] + bq.z;
      float v3 = acc[i][jt][3] + bq.w;
      const long doff = ((long)(b * 16 + hh) * 1024 + l) * 64 + d;
      if (three == 2) {
        uint2 o = {pack2_bf16(v0, v1), pack2_bf16(v2, v3)};
        *(uint2*)&vbuf[doff] = o;
      } else {
        const float4 cs = *(const float4*)&cosT[l * 32 + (d & 31)];
        const float4 sn = *(const float4*)&sinT[l * 32 + (d & 31)];
        float e0 = v0 * cs.x - v1 * sn.x;
        float o0 = v1 * cs.y + v0 * sn.y;
        float e1 = v2 * cs.z - v3 * sn.z;
        float o1 = v3 * cs.w + v2 * sn.w;
        short* dst;
        if (three == 0) {
          const float S = 0.18033688011f;  // 1/sqrt(D) * log2(e)
          e0 *= S; o0 *= S; e1 *= S; o1 *= S;
          dst = qb;
        } else {
          dst = kbuf;
        }
        uint2 o = {pack2_bf16(e0, o0), pack2_bf16(e1, o1)};
        *(uint2*)&dst[doff] = o;
      }
    }
  }
}

// ---------------- V transpose: (B,H,L,D) -> (B,H,D,L) ----------------
__global__ __launch_bounds__(256) void transpose_v(const short* __restrict__ vbuf,
                                                   short* __restrict__ vTb) {
  __shared__ short T[64 * 72];
  const int bh = blockIdx.y;
  const int l0 = blockIdx.x * 64;
  const int t = threadIdx.x;
  const int row = t >> 3;
  const int cc = (t & 7) * 8;
  const short* src = vbuf + ((long)bh * 1024 + l0) * 64;
  for (int p = 0; p < 2; p++) {
    int lr = row + p * 32;
    *(bf16x8*)&T[lr * 72 + cc] = *(const bf16x8*)&src[(long)lr * 64 + cc];
  }
  __syncthreads();
  short* dst = vTb + (long)bh * 64 * 1024 + l0;
  for (int p = 0; p < 2; p++) {
    int d = row + p * 32;
    bf16x8 v;
    for (int j = 0; j < 8; j++) v[j] = T[(cc + j) * 72 + d];
    *(bf16x8*)&dst[(long)d * 1024 + cc] = v;
  }
}

// ---------------- flash attention v6 ----------------
// = R4 structure (256 thr, 4 waves x 16 q-rows, dbuf global_load_lds staging,
// register P, ones-row MFMA row-sum) with the u64 bitmask (1 MB, L3-resident)
// expanded in-register to bf16 AND-masks. VGPR budget ~48 -> bounds (256,5), no spill.
__global__ __launch_bounds__(256, 5) void flash_attn(
    const short* __restrict__ qb, const short* __restrict__ kbuf,
    const short* __restrict__ vTb, const u64* __restrict__ maskb,
    short* __restrict__ attno) {
  __shared__ short K0[64 * 64], K1[64 * 64];
  __shared__ short V0[64 * 64], V1[64 * 64];
  const int t = threadIdx.x;
  const int wid = t >> 6, lane = t & 63;
  const int g = lane >> 4, c = lane & 15;
  const int q0 = blockIdx.x * 64;
  const int bh = blockIdx.y;
  const int b = bh >> 4;
  const int h = bh & 15;
  const long qoff = (long)bh * 1024 * 64;
  const int qrow = q0 + wid * 16 + c;  // this lane's q column

  // Q fragment (B-operand of S^T mfma)
  bf16x8 aq0, aq1;
  {
    const short* qp = qb + qoff + (long)qrow * 64;
    aq0 = *(const bf16x8*)(qp + g * 8);
    aq1 = *(const bf16x8*)(qp + 32 + g * 8);
  }

  f32x4 Od[4];
  for (int i = 0; i < 4; i++) Od[i] = (f32x4){0.f, 0.f, 0.f, 0.f};
  f32x4 Ld = (f32x4){0.f, 0.f, 0.f, 0.f};  // row-sum acc: D[0][q] = sum_k P[k][q]
  float m_run = -1e30f;

  // ones-row A-operand: lanes with m-index 0 hold bf16 1.0 across k
  bf16x4 avOnes;
  {
    union { bf16x4 v; u32 u[2]; } av;
    av.u[0] = av.u[1] = (c == 0) ? 0x3F803F80u : 0u;
    avOnes = av.v;
  }

  const u64* mrow = maskb + ((long)b * 1024 + qrow) * 16;
  const short* Kg = kbuf + qoff;
  const short* Vg = vTb + qoff;

  // staging: wave w covers rows w*16..w*16+15; lane l fetches global chunk
  // (l&7)^(l>>3) of row base+(l>>3) -> lands at LDS chunk pos l&7 (xor swizzle).
  const int l8 = lane >> 3, l7 = lane & 7;
  const int sr = wid * 16 + l8;
  const int sch = ((l7 ^ l8) & 7) * 8;

  // fragment read offsets (shorts, within a 64x64 tile buffer)
  const int ck0 = g ^ (c & 7);
  const int kOff0 = c * 64 + ck0 * 8;
  const int kOff1 = c * 64 + (ck0 ^ 4) * 8;
  int vOff[4];
  for (int nt = 0; nt < 4; nt++)
    vOff[nt] = c * 64 + (((2 * nt + (g >> 1)) ^ (c & 7)) * 8) + (g & 1) * 4;

#define STAGE(KD, VD, ktn) do { \
    GLD_LDS16(Kg + (long)((ktn) + sr) * 64 + sch,       &KD[(wid * 16) * 64]); \
    GLD_LDS16(Kg + (long)((ktn) + sr + 8) * 64 + sch,   &KD[(wid * 16 + 8) * 64]); \
    GLD_LDS16(Vg + (long)sr * 1024 + (ktn) + sch,       &VD[(wid * 16) * 64]); \
    GLD_LDS16(Vg + (long)(sr + 8) * 1024 + (ktn) + sch, &VD[(wid * 16 + 8) * 64]); \
  } while (0)

#define TILE(KB, VB, KP, VP, ki) do { \
    u64 mw = mrow[ki]; /* L3-resident, issued before the barrier */ \
    __syncthreads(); /* drains prefetch issued a full tile of compute ago */ \
    STAGE(KP, VP, (((ki) + 1) & 15) * 64); \
    f32x4 z[4]; \
    for (int nt = 0; nt < 4; nt++) { \
      bf16x8 bk0 = *(const bf16x8*)&KB[kOff0 + nt * 1024]; \
      bf16x8 bk1 = *(const bf16x8*)&KB[kOff1 + nt * 1024]; \
      f32x4 zz = (f32x4){0.f, 0.f, 0.f, 0.f}; \
      zz = __builtin_amdgcn_mfma_f32_16x16x32_bf16(bk0, aq0, zz, 0, 0, 0); \
      zz = __builtin_amdgcn_mfma_f32_16x16x32_bf16(bk1, aq1, zz, 0, 0, 0); \
      z[nt] = zz; \
    } \
    float mx = fmaxf(fmaxf(z[0][0], z[0][1]), fmaxf(z[0][2], z[0][3])); \
    for (int nt = 1; nt < 4; nt++) \
      mx = fmaxf(mx, fmaxf(fmaxf(z[nt][0], z[nt][1]), fmaxf(z[nt][2], z[nt][3]))); \
    mx = fmaxf(mx, __shfl_xor(mx, 16, 64)); \
    mx = fmaxf(mx, __shfl_xor(mx, 32, 64)); \
    float mnew = fmaxf(m_run, mx); \
    if (__ballot(mnew > m_run)) { \
      float al = exp2_fast(m_run - mnew); \
      for (int dt = 0; dt < 4; dt++) { \
        Od[dt][0] *= al; Od[dt][1] *= al; Od[dt][2] *= al; Od[dt][3] *= al; \
      } \
      Ld[0] *= al; \
      m_run = mnew; \
    } \
    bf16x4 pb[4]; \
    for (int nt = 0; nt < 4; nt++) { \
      u32 m4 = (u32)(mw >> (nt * 16 + g * 4)) & 0xFu; \
      u32 mlo = ((m4 & 1u) ? 0xFFFFu : 0u) | ((m4 & 2u) ? 0xFFFF0000u : 0u); \
      u32 mhi = ((m4 & 4u) ? 0xFFFFu : 0u) | ((m4 & 8u) ? 0xFFFF0000u : 0u); \
      float p0 = exp2_fast(z[nt][0] - mnew); \
      float p1 = exp2_fast(z[nt][1] - mnew); \
      float p2 = exp2_fast(z[nt][2] - mnew); \
      float p3 = exp2_fast(z[nt][3] - mnew); \
      union { bf16x4 v; u32 u[2]; } pu; \
      pu.u[0] = pack2_bf16(p0, p1) & mlo; \
      pu.u[1] = pack2_bf16(p2, p3) & mhi; \
      pb[nt] = pu.v; \
    } \
    for (int nt = 0; nt < 4; nt++) { \
      Ld = mfma_16x16x16_bf16(avOnes, pb[nt], Ld); \
      for (int dt = 0; dt < 4; dt++) { \
        bf16x4 av = *(const bf16x4*)&VB[vOff[nt] + dt * 1024]; \
        Od[dt] = mfma_16x16x16_bf16(av, pb[nt], Od[dt]); \
      } \
    } \
  } while (0)

  STAGE(K0, V0, 0);
  for (int ki = 0; ki < 16; ki += 2) {
    TILE(K0, V0, K1, V1, ki);
    TILE(K1, V1, K0, V0, ki + 1);
  }
#undef TILE
#undef STAGE

  // l for q=c lives in lane c (reg 0 of quad 0); broadcast then normalize+store
  float lsum = __shfl(Ld[0], c, 64);
  float inv = 1.f / lsum;
  long rbase = ((long)qrow * 8 + b) * 1024 + h * 64 + g * 4;
  for (int dt = 0; dt < 4; dt++) {
    union { bf16x4 v; u32 u[2]; } o;
    o.u[0] = pack2_bf16(Od[dt][0] * inv, Od[dt][1] * inv);
    o.u[1] = pack2_bf16(Od[dt][2] * inv, Od[dt][3] * inv);
    *(bf16x4*)&attno[rbase + dt * 16] = o.v;
  }
}

// ---------------- GEMM 2: out = attno * Wo^T + bo (f32 out) ----------------
__global__ __launch_bounds__(256, 2) void gemm_out(
    const short* __restrict__ Ab, const short* __restrict__ Wob,
    const float* __restrict__ bo, float* __restrict__ out) {
  __shared__ short Ash[128 * 32];
  __shared__ short Bsh[128 * 32];
  const int tid = threadIdx.x;
  const int wid = tid >> 6, lane = tid & 63;
  const int g = lane >> 4, c = lane & 15;
  const int wm = wid >> 1, wn = wid & 1;
  const int m0 = blockIdx.y * 128, n0 = blockIdx.x * 128;

  f32x4 acc[4][4];
  for (int i = 0; i < 4; i++)
    for (int j = 0; j < 4; j++) acc[i][j] = (f32x4){0.f, 0.f, 0.f, 0.f};

  const int srow = lane >> 2;
  const int scol = (lane & 3) * 8;
  const short* AgL = Ab + (long)(m0 + wid * 32 + srow) * 1024 + scol;
  const short* BgL = Wob + (long)(n0 + wid * 32 + srow) * 1024 + scol;
  short* As0 = &Ash[(wid * 32) * 32];
  short* As1 = &Ash[(wid * 32 + 16) * 32];
  short* Bs0 = &Bsh[(wid * 32) * 32];
  short* Bs1 = &Bsh[(wid * 32 + 16) * 32];

  for (int kt = 0; kt < 32; ++kt) {
    const int ko = kt * 32;
    GLD_LDS16(AgL + ko, As0);
    GLD_LDS16(AgL + ko + 16 * 1024, As1);
    GLD_LDS16(BgL + ko, Bs0);
    GLD_LDS16(BgL + ko + 16 * 1024, Bs1);
    __syncthreads();
    bf16x8 af[4], bfr[4];
    for (int i = 0; i < 4; i++)
      af[i] = *(const bf16x8*)&Ash[(wm * 64 + i * 16 + c) * 32 + g * 8];
    for (int j = 0; j < 4; j++)
      bfr[j] = *(const bf16x8*)&Bsh[(wn * 64 + j * 16 + c) * 32 + g * 8];
    for (int i = 0; i < 4; i++)
      for (int j = 0; j < 4; j++)
        acc[i][j] = __builtin_amdgcn_mfma_f32_16x16x32_bf16(af[i], bfr[j], acc[i][j], 0, 0, 0);
    __syncthreads();
  }

  for (int jt = 0; jt < 4; jt++) {
    const int j = n0 + wn * 64 + jt * 16 + c;
    const float bias = bo[j];
    for (int i = 0; i < 4; i++) {
      const int rbase = m0 + wm * 64 + i * 16 + g * 4;
      for (int reg = 0; reg < 4; reg++)
        out[(long)(rbase + reg) * 1024 + j] = acc[i][jt][reg] + bias;
    }
  }
}

// ---------------- launcher ----------------
extern "C" void kernel_launch(void* const* d_in, const int* in_sizes, int n_in,
                              void* d_out, int out_size, void* d_ws, size_t ws_size,
                              hipStream_t stream) {
  const float* hs = (const float*)d_in[0];
  const float* rpe = (const float*)d_in[1];
  const int* amask = (const int*)d_in[2];
  const float* Wqkv = (const float*)d_in[3];
  const float* bqkv = (const float*)d_in[4];
  const float* Wo = (const float*)d_in[5];
  const float* bo = (const float*)d_in[6];
  float* out = (float*)d_out;

  char* ws = (char*)d_ws;
  auto alloc = [&](size_t bytes) {
    char* p = ws;
    ws += (bytes + 255) & ~(size_t)255;
    return p;
  };
  short* Xb = (short*)alloc(8192LL * 1024 * 2);
  short* Wqkvb = (short*)alloc(3072LL * 1024 * 2);
  short* Wob = (short*)alloc(1024LL * 1024 * 2);
  float* cosT = (float*)alloc(1024 * 32 * 4);
  float* sinT = (float*)alloc(1024 * 32 * 4);
  u64* maskb = (u64*)alloc(8LL * 1024 * 16 * 8);
  short* qb = (short*)alloc(128LL * 1024 * 64 * 2);
  short* kbuf = (short*)alloc(128LL * 1024 * 64 * 2);
  short* vbuf = (short*)alloc(128LL * 1024 * 64 * 2);
  short* vTb = (short*)alloc(128LL * 1024 * 64 * 2);
  short* attno = (short*)alloc(8192LL * 1024 * 2);

  cvt_f32_bf16<<<8192 * 1024 / 4 / 256, 256, 0, stream>>>(hs, Xb, 8192 * 1024);
  cvt_f32_bf16<<<3072 * 1024 / 4 / 256, 256, 0, stream>>>(Wqkv, Wqkvb, 3072 * 1024);
  cvt_f32_bf16<<<1024 * 1024 / 4 / 256, 256, 0, stream>>>(Wo, Wob, 1024 * 1024);
  rope_tables<<<128, 256, 0, stream>>>(rpe, cosT, sinT);
  mask_pack<<<32768, 256, 0, stream>>>(amask, maskb);
  gemm_qkv<<<dim3(24, 64), 256, 0, stream>>>(Xb, Wqkvb, bqkv, cosT, sinT, qb, kbuf, vbuf);
  transpose_v<<<dim3(16, 128), 256, 0, stream>>>(vbuf, vTb);
  flash_attn<<<dim3(16, 128), 256, 0, stream>>>(qb, kbuf, vTb, maskb, attno);
  gemm_out<<<dim3(8, 64), 256, 0, stream>>>(attno, Wob, bo, out);
}